// Round 5
// baseline (442.737 us; speedup 1.0000x reference)
//
#include <hip/hip_runtime.h>
#include <math.h>

// TemporalSNNClassifier — bit-exact fp32 emulation (absmax 0.0 since r2).
//
// r2/r3/r4 all plateaued at ~360us despite different schedules -> the
// common factor was the fully-unrolled t-loop: ~35k instructions (~280 KB)
// of straight-line code vs 32 KB I$ -> instruction-fetch bound.
// r5: t-loop ROLLED (unroll 1, x2 steps for static double-buffer index,
// ~8 KB body, I$-resident); GEMM k-loop rolled too. 128-thread blocks,
// 16 rows, 1024 blocks = 4 blocks/CU -> cheap 2-wave barriers, block-level
// interleaving across barrier stalls.
//
// FROZEN numerics: k-ascending single-accumulator chains for both GEMMs
// (h ascending 0..127 in layer 2), bias as one separate add, leaky update
// ((0.9f*mem)+cur)-reset with contraction off, spike <=> mem > 1.0f,
// reset_t == spk_{t-1}; masked add (bit ? w : +0.0f) is bit-identical to
// fmaf(s,w,a) for s in {0,1} since the accumulator is never -0.

#define T_STEPS 64
#define IN_DIM  256
#define HID     128
#define NCLS    8
#define RPB     16    // rows per block
#define NTHR    128   // 2 waves per block

// masked add term: bit b of m set -> w, else +0.0f (v_bfe_i32 + v_and).
__device__ __forceinline__ float mand(unsigned int m, int b, float w) {
    int sel = ((int)(m << (31 - b))) >> 31;   // compiler folds to v_bfe_i32
    return __int_as_float(sel & __float_as_int(w));
}

__global__ __launch_bounds__(NTHR, 2)
void snn_fp32(const float* __restrict__ x, const float* __restrict__ W1,
              const float* __restrict__ b1, const float* __restrict__ W2,
              const float* __restrict__ b2, float* __restrict__ out)
{
#pragma clang fp contract(off)
    __shared__ unsigned short smask[2][RPB * 8];   // [buf][row*8+q]
    __shared__ float w2s[NCLS][HID + 4];           // stride 132: class rows on
                                                   // disjoint bank quads

    const int tid = threadIdx.x;
    const int r   = tid >> 3;            // phase-a row (0..15)
    const int q   = tid & 7;             // phase-a h-block (16 contiguous h)
    const int row = blockIdx.x * RPB + r;

    // ---- stage W2 into LDS: 128 threads x 2 float4 ----
    {
        const int c = tid >> 4;          // class 0..7
        const int g = tid & 15;          // float4 index
        const float4 v0 = *(const float4*)(W2 + c * HID + 4 * g);
        const float4 v1 = *(const float4*)(W2 + c * HID + 64 + 4 * g);
        w2s[c][4 * g + 0] = v0.x; w2s[c][4 * g + 1] = v0.y;
        w2s[c][4 * g + 2] = v0.z; w2s[c][4 * g + 3] = v0.w;
        w2s[c][64 + 4 * g + 0] = v1.x; w2s[c][64 + 4 * g + 1] = v1.y;
        w2s[c][64 + 4 * g + 2] = v1.z; w2s[c][64 + 4 * g + 3] = v1.w;
    }

    // ---- cur1[h] = fmaf-chain_k( x[row,k]*W1[h,k] ) + b1[h], h=q*16+i ----
    float cur1[16];
    #pragma unroll
    for (int i = 0; i < 16; ++i) cur1[i] = 0.0f;

    const float* xrow = x + (size_t)row * IN_DIM;
    const float* w1b  = W1 + (size_t)(q * 16) * IN_DIM;
    #pragma unroll 1
    for (int k = 0; k < IN_DIM; k += 4) {         // ROLLED: ~100-instr body
        const float4 xv = *(const float4*)(xrow + k);
        #pragma unroll
        for (int i = 0; i < 16; ++i) {
            const float4 wv = *(const float4*)(w1b + i * IN_DIM + k);
            float c = cur1[i];
            c = fmaf(xv.x, wv.x, c);     // k ascending, single accumulator
            c = fmaf(xv.y, wv.y, c);
            c = fmaf(xv.z, wv.z, c);
            c = fmaf(xv.w, wv.w, c);
            cur1[i] = c;
        }
    }
    #pragma unroll
    for (int i = 0; i < 16; ++i)
        cur1[i] = cur1[i] + b1[q * 16 + i];

    // ---- phase-b identity: cls = tid>>4 (8 classes), brow = tid&15 ----
    const int cls  = tid >> 4;
    const int brow = tid & 15;
    const float b2c = b2[cls];
    const float* __restrict__ wrow = &w2s[cls][0];

    float mem1[16], spk1[16];
    #pragma unroll
    for (int i = 0; i < 16; ++i) { mem1[i] = 0.0f; spk1[i] = 0.0f; }
    float m2 = 0.0f, r2 = 0.0f, o = 0.0f;

    auto step = [&](int buf) __attribute__((always_inline)) {
        // phase a: layer-1 leaky update for 16 h units (numpy op order)
        unsigned int mk = 0;
        #pragma unroll
        for (int i = 0; i < 16; ++i) {
            float tmp = 0.9f * mem1[i];   // rounded mul
            tmp = tmp + cur1[i];          // rounded add
            float m = tmp - spk1[i];      // rounded sub
            mem1[i] = m;
            const bool fire = (m > 1.0f);
            spk1[i] = fire ? 1.0f : 0.0f;
            mk |= fire ? (1u << i) : 0u;
        }
        smask[buf][r * 8 + q] = (unsigned short)mk;
        __syncthreads();   // double buffer -> one barrier per timestep

        // phase b: h-ascending 128-step masked-add chain (bit-exact)
        const uint4 mv = *(const uint4*)&smask[buf][brow * 8];
        const unsigned int mw[4] = {mv.x, mv.y, mv.z, mv.w};
        float a = 0.0f;
        #pragma unroll
        for (int j = 0; j < 4; ++j) {
            const unsigned int m = mw[j];
            #pragma unroll
            for (int g = 0; g < 8; ++g) {
                const float4 wv = *(const float4*)(wrow + j * 32 + 4 * g);
                a = a + mand(m, 4 * g + 0, wv.x);   // strict h order
                a = a + mand(m, 4 * g + 1, wv.y);
                a = a + mand(m, 4 * g + 2, wv.z);
                a = a + mand(m, 4 * g + 3, wv.w);
            }
        }
        const float c2 = a + b2c;
        float t2 = 0.9f * m2; t2 = t2 + c2; m2 = t2 - r2;
        r2 = (m2 > 1.0f) ? 1.0f : 0.0f;
        o  = o + r2;
    };

    // ROLLED temporal loop: body ~1000 instrs (~8 KB), I$-resident.
    #pragma unroll 1
    for (int tt = 0; tt < T_STEPS / 2; ++tt) {
        step(0);
        step(1);
    }

    out[(size_t)(blockIdx.x * RPB + brow) * NCLS + cls] = o;
}

extern "C" void kernel_launch(void* const* d_in, const int* in_sizes, int n_in,
                              void* d_out, int out_size, void* d_ws, size_t ws_size,
                              hipStream_t stream) {
    const float* x  = (const float*)d_in[0];
    const float* W1 = (const float*)d_in[1];
    const float* b1 = (const float*)d_in[2];
    const float* W2 = (const float*)d_in[3];
    const float* b2 = (const float*)d_in[4];
    float* out = (float*)d_out;

    const int batch = in_sizes[0] / IN_DIM;   // 16384
    const int grid  = batch / RPB;            // 1024 blocks, 4 per CU
    snn_fp32<<<grid, NTHR, 0, stream>>>(x, W1, b1, W2, b2, out);
}

// Round 6
// 393.933 us; speedup vs baseline: 1.1239x; 1.1239x over previous
//
#include <hip/hip_runtime.h>
#include <math.h>

// TemporalSNNClassifier — bit-exact fp32 emulation (absmax 0.0 since r2).
//
// r2-r5 all ~360-440us: waves parked on in-loop LDS latency (32
// ds_read_b128/t for W2) + per-timestep barrier, with only 2 waves/SIMD to
// hide it. VGPR_Count=52 == 48 state floats + temps -> small arrays DO
// promote; r3's 128-float array hit SROA's size limit (alloca->scratch).
//
// r6: wave-autonomous. One wave = 8 rows x 8 classes. W2 row per lane in 32
// explicit float4 SSA locals (forced VGPR). Masks cross lanes via
// shfl_xor pair-pack + 4 ds_bpermute. Zero __syncthreads in the t-loop,
// zero in-loop LDS arrays, chain step = bfe+and+add (3 VALU).
//
// FROZEN numerics: k-ascending single-accumulator fmaf chains (GEMM1),
// h-ascending 0..127 masked-add chain (==fmaf(s,w,a), s in {0,1}, acc never
// -0), bias as one separate add, leaky update ((0.9f*mem)+cur)-reset with
// contraction off, spike <=> mem > 1.0f, reset_t == spk_{t-1}.

#define T_STEPS 64
#define IN_DIM  256
#define HID     128
#define NCLS    8
#define RPB     32    // rows per block (4 waves x 8 rows)
#define NTHR    256

// masked add term: bit b of m set -> w, else +0.0f (v_bfe_i32 + v_and).
__device__ __forceinline__ float mand(unsigned int m, int b, float w) {
    int sel = ((int)(m << (31 - b))) >> 31;
    return __int_as_float(sel & __float_as_int(w));
}

__global__ __launch_bounds__(NTHR, 2)
void snn_fp32(const float* __restrict__ x, const float* __restrict__ W1,
              const float* __restrict__ b1, const float* __restrict__ W2,
              const float* __restrict__ b2, float* __restrict__ out)
{
#pragma clang fp contract(off)
    const int tid  = threadIdx.x;
    const int lane = tid & 63;
    const int r    = tid >> 3;           // block row 0..31 (wave w owns 8w..8w+7)
    const int q    = tid & 7;            // phase-a h-block / phase-b class
    const int row  = blockIdx.x * RPB + r;

    // ---- GEMM1: cur1[h] = fmaf-chain_k( x[row,k]*W1[h,k] ) + b1[h] ----
    float cur1[16];
    #pragma unroll
    for (int i = 0; i < 16; ++i) cur1[i] = 0.0f;

    const float* xrow = x + (size_t)row * IN_DIM;
    const float* w1b  = W1 + (size_t)(q * 16) * IN_DIM;
    #pragma unroll 1
    for (int k = 0; k < IN_DIM; k += 4) {
        const float4 xv = *(const float4*)(xrow + k);
        #pragma unroll
        for (int i = 0; i < 16; ++i) {
            const float4 wv = *(const float4*)(w1b + i * IN_DIM + k);
            float c = cur1[i];
            c = fmaf(xv.x, wv.x, c);     // k ascending, single accumulator
            c = fmaf(xv.y, wv.y, c);
            c = fmaf(xv.z, wv.z, c);
            c = fmaf(xv.w, wv.w, c);
            cur1[i] = c;
        }
    }
    #pragma unroll
    for (int i = 0; i < 16; ++i)
        cur1[i] = cur1[i] + b1[q * 16 + i];

    // ---- W2[class=q][*] into 32 explicit float4 SSA locals (VGPRs) ----
    const float* wsrc = W2 + (size_t)q * HID;
#define LDW2(n) const float4 w2_##n = *(const float4*)(wsrc + 4 * (n));
    LDW2(0)  LDW2(1)  LDW2(2)  LDW2(3)  LDW2(4)  LDW2(5)  LDW2(6)  LDW2(7)
    LDW2(8)  LDW2(9)  LDW2(10) LDW2(11) LDW2(12) LDW2(13) LDW2(14) LDW2(15)
    LDW2(16) LDW2(17) LDW2(18) LDW2(19) LDW2(20) LDW2(21) LDW2(22) LDW2(23)
    LDW2(24) LDW2(25) LDW2(26) LDW2(27) LDW2(28) LDW2(29) LDW2(30) LDW2(31)
#undef LDW2
    const float b2c = b2[q];

    // bpermute byte-addresses for words 0..3 of this lane's row
    const int pbase = (lane << 2) & 0xE0;    // (lane&0x38)*4

    float mem1[16];
    #pragma unroll
    for (int i = 0; i < 16; ++i) mem1[i] = 0.0f;
    unsigned int pmk = 0;                // previous spike mask (reset source)
    float m2 = 0.0f, r2 = 0.0f, o = 0.0f;

    #pragma unroll 1
    for (int t = 0; t < T_STEPS; ++t) {
        // phase a: leaky layer-1 for 16 h units (numpy op order, no contract)
        unsigned int mk = 0;
        #pragma unroll
        for (int i = 0; i < 16; ++i) {
            float tmp = 0.9f * mem1[i];            // rounded mul
            tmp = tmp + cur1[i];                   // rounded add
            float m = tmp - mand(pmk, i, 1.0f);    // rounded sub (reset=prev spk)
            mem1[i] = m;
            mk |= (m > 1.0f) ? (1u << i) : 0u;
        }
        pmk = mk;

        // pack pairs: even-q lanes hold word for (q, q+1)
        const int nb = __shfl_xor((int)mk, 1, 64);
        const int lo = (q & 1) ? nb : (int)mk;
        const int hi = (q & 1) ? (int)mk : nb;
        const int word = lo | (hi << 16);

        // pull this row's 4 words from lanes (row*8 + 2j)
        const unsigned int m0 = (unsigned int)__builtin_amdgcn_ds_bpermute(pbase + 0,  word);
        const unsigned int m1 = (unsigned int)__builtin_amdgcn_ds_bpermute(pbase + 8,  word);
        const unsigned int m2w = (unsigned int)__builtin_amdgcn_ds_bpermute(pbase + 16, word);
        const unsigned int m3 = (unsigned int)__builtin_amdgcn_ds_bpermute(pbase + 24, word);

        // phase b: h-ascending 128-step masked-add chain, all-register
        float a = 0.0f;
#define STEP4(mw, vec, b0) \
        a = a + mand(mw, (b0) + 0, (vec).x); \
        a = a + mand(mw, (b0) + 1, (vec).y); \
        a = a + mand(mw, (b0) + 2, (vec).z); \
        a = a + mand(mw, (b0) + 3, (vec).w);
        STEP4(m0, w2_0,  0)  STEP4(m0, w2_1,  4)  STEP4(m0, w2_2,  8)  STEP4(m0, w2_3,  12)
        STEP4(m0, w2_4,  16) STEP4(m0, w2_5,  20) STEP4(m0, w2_6,  24) STEP4(m0, w2_7,  28)
        STEP4(m1, w2_8,  0)  STEP4(m1, w2_9,  4)  STEP4(m1, w2_10, 8)  STEP4(m1, w2_11, 12)
        STEP4(m1, w2_12, 16) STEP4(m1, w2_13, 20) STEP4(m1, w2_14, 24) STEP4(m1, w2_15, 28)
        STEP4(m2w, w2_16, 0)  STEP4(m2w, w2_17, 4)  STEP4(m2w, w2_18, 8)  STEP4(m2w, w2_19, 12)
        STEP4(m2w, w2_20, 16) STEP4(m2w, w2_21, 20) STEP4(m2w, w2_22, 24) STEP4(m2w, w2_23, 28)
        STEP4(m3, w2_24, 0)  STEP4(m3, w2_25, 4)  STEP4(m3, w2_26, 8)  STEP4(m3, w2_27, 12)
        STEP4(m3, w2_28, 16) STEP4(m3, w2_29, 20) STEP4(m3, w2_30, 24) STEP4(m3, w2_31, 28)
#undef STEP4

        // layer-2 leaky update (numpy op order)
        const float c2 = a + b2c;
        float t2 = 0.9f * m2; t2 = t2 + c2; m2 = t2 - r2;
        r2 = (m2 > 1.0f) ? 1.0f : 0.0f;
        o  = o + r2;
    }

    // chain lane (row = r, class = q) -> out[...] : coalesced (out + blk*256 + tid)
    out[(size_t)row * NCLS + q] = o;
}

extern "C" void kernel_launch(void* const* d_in, const int* in_sizes, int n_in,
                              void* d_out, int out_size, void* d_ws, size_t ws_size,
                              hipStream_t stream) {
    const float* x  = (const float*)d_in[0];
    const float* W1 = (const float*)d_in[1];
    const float* b1 = (const float*)d_in[2];
    const float* W2 = (const float*)d_in[3];
    const float* b2 = (const float*)d_in[4];
    float* out = (float*)d_out;

    const int batch = in_sizes[0] / IN_DIM;   // 16384
    const int grid  = batch / RPB;            // 512 blocks
    snn_fp32<<<grid, NTHR, 0, stream>>>(x, W1, b1, W2, b2, out);
}

// Round 7
// 369.922 us; speedup vs baseline: 1.1968x; 1.0649x over previous
//
#include <hip/hip_runtime.h>
#include <math.h>

// TemporalSNNClassifier — bit-exact fp32 emulation (absmax 0.0 since r2).
//
// r6 evidence: VGPR_Count=128 (granule cap) with ~180 needed -> compiler
// sank the 32 loop-invariant W2 float4 loads INTO the t-loop (no scratch
// writes, no FETCH growth => L1/L2 reloads each timestep); 2 waves/SIMD
// can't hide the ~200cyc hit latency -> VALUBusy 45%, dur 345us.
// r7: __launch_bounds__(256,1) lifts the VGPR budget to 512 (occupancy is
// grid-limited at 2 waves/SIMD regardless, so big VGPR counts are FREE).
// W2 stays register-resident; chain step forced to v_bfe_i32+and+add.
//
// FROZEN numerics: k-ascending single-accumulator fmaf chains (GEMM1),
// h-ascending 0..127 masked-add chain (==fmaf(s,w,a), s in {0,1}, acc never
// -0), bias as one separate add, leaky update ((0.9f*mem)+cur)-reset with
// contraction off, spike <=> mem > 1.0f, reset_t == spk_{t-1}.

#define T_STEPS 64
#define IN_DIM  256
#define HID     128
#define NCLS    8
#define RPB     32    // rows per block (4 waves x 8 rows)
#define NTHR    256

// masked add term: bit b of m set -> w, else +0.0f (v_bfe_i32 + v_and).
__device__ __forceinline__ float mand(unsigned int m, int b, float w) {
#if __has_builtin(__builtin_amdgcn_sbfe)
    int sel = __builtin_amdgcn_sbfe((int)m, b, 1);   // 0 or -1, 1 VALU op
#else
    int sel = ((int)(m << (31 - b))) >> 31;          // folds to v_bfe_i32
#endif
    return __int_as_float(sel & __float_as_int(w));
}

__global__ __launch_bounds__(NTHR, 1)
void snn_fp32(const float* __restrict__ x, const float* __restrict__ W1,
              const float* __restrict__ b1, const float* __restrict__ W2,
              const float* __restrict__ b2, float* __restrict__ out)
{
#pragma clang fp contract(off)
    const int tid  = threadIdx.x;
    const int lane = tid & 63;
    const int r    = tid >> 3;           // block row 0..31 (wave w owns 8w..8w+7)
    const int q    = tid & 7;            // phase-a h-block / phase-b class
    const int row  = blockIdx.x * RPB + r;

    // ---- GEMM1: cur1[h] = fmaf-chain_k( x[row,k]*W1[h,k] ) + b1[h] ----
    float cur1[16];
    #pragma unroll
    for (int i = 0; i < 16; ++i) cur1[i] = 0.0f;

    const float* xrow = x + (size_t)row * IN_DIM;
    const float* w1b  = W1 + (size_t)(q * 16) * IN_DIM;
    #pragma unroll 1
    for (int k = 0; k < IN_DIM; k += 4) {
        const float4 xv = *(const float4*)(xrow + k);
        #pragma unroll
        for (int i = 0; i < 16; ++i) {
            const float4 wv = *(const float4*)(w1b + i * IN_DIM + k);
            float c = cur1[i];
            c = fmaf(xv.x, wv.x, c);     // k ascending, single accumulator
            c = fmaf(xv.y, wv.y, c);
            c = fmaf(xv.z, wv.z, c);
            c = fmaf(xv.w, wv.w, c);
            cur1[i] = c;
        }
    }
    #pragma unroll
    for (int i = 0; i < 16; ++i)
        cur1[i] = cur1[i] + b1[q * 16 + i];

    // ---- W2[class=q][*] into 32 explicit float4 SSA locals (VGPRs) ----
    const float* wsrc = W2 + (size_t)q * HID;
#define LDW2(n) const float4 w2_##n = *(const float4*)(wsrc + 4 * (n));
    LDW2(0)  LDW2(1)  LDW2(2)  LDW2(3)  LDW2(4)  LDW2(5)  LDW2(6)  LDW2(7)
    LDW2(8)  LDW2(9)  LDW2(10) LDW2(11) LDW2(12) LDW2(13) LDW2(14) LDW2(15)
    LDW2(16) LDW2(17) LDW2(18) LDW2(19) LDW2(20) LDW2(21) LDW2(22) LDW2(23)
    LDW2(24) LDW2(25) LDW2(26) LDW2(27) LDW2(28) LDW2(29) LDW2(30) LDW2(31)
#undef LDW2
    const float b2c = b2[q];

    // bpermute byte-addresses for words 0..3 of this lane's row
    const int pbase = (lane << 2) & 0xE0;    // (lane&0x38)*4

    float mem1[16];
    #pragma unroll
    for (int i = 0; i < 16; ++i) mem1[i] = 0.0f;
    unsigned int pmk = 0;                // previous spike mask (reset source)
    float m2 = 0.0f, r2 = 0.0f, o = 0.0f;

    #pragma unroll 1
    for (int t = 0; t < T_STEPS; ++t) {
        // phase a: leaky layer-1 for 16 h units (numpy op order, no contract)
        unsigned int mk = 0;
        #pragma unroll
        for (int i = 0; i < 16; ++i) {
            float tmp = 0.9f * mem1[i];            // rounded mul
            tmp = tmp + cur1[i];                   // rounded add
            float m = tmp - mand(pmk, i, 1.0f);    // rounded sub (reset=prev spk)
            mem1[i] = m;
            mk |= (m > 1.0f) ? (1u << i) : 0u;
        }
        pmk = mk;

        // pack pairs: even-q lanes hold word for (q, q+1)
        const int nb = __shfl_xor((int)mk, 1, 64);
        const int lo = (q & 1) ? nb : (int)mk;
        const int hi = (q & 1) ? (int)mk : nb;
        const int word = lo | (hi << 16);

        // pull this row's 4 words from lanes (row*8 + 2j)
        const unsigned int m0 = (unsigned int)__builtin_amdgcn_ds_bpermute(pbase + 0,  word);
        const unsigned int m1 = (unsigned int)__builtin_amdgcn_ds_bpermute(pbase + 8,  word);
        const unsigned int m2w = (unsigned int)__builtin_amdgcn_ds_bpermute(pbase + 16, word);
        const unsigned int m3 = (unsigned int)__builtin_amdgcn_ds_bpermute(pbase + 24, word);

        // phase b: h-ascending 128-step masked-add chain, all-register
        float a = 0.0f;
#define STEP4(mw, vec, b0) \
        a = a + mand(mw, (b0) + 0, (vec).x); \
        a = a + mand(mw, (b0) + 1, (vec).y); \
        a = a + mand(mw, (b0) + 2, (vec).z); \
        a = a + mand(mw, (b0) + 3, (vec).w);
        STEP4(m0, w2_0,  0)  STEP4(m0, w2_1,  4)  STEP4(m0, w2_2,  8)  STEP4(m0, w2_3,  12)
        STEP4(m0, w2_4,  16) STEP4(m0, w2_5,  20) STEP4(m0, w2_6,  24) STEP4(m0, w2_7,  28)
        STEP4(m1, w2_8,  0)  STEP4(m1, w2_9,  4)  STEP4(m1, w2_10, 8)  STEP4(m1, w2_11, 12)
        STEP4(m1, w2_12, 16) STEP4(m1, w2_13, 20) STEP4(m1, w2_14, 24) STEP4(m1, w2_15, 28)
        STEP4(m2w, w2_16, 0)  STEP4(m2w, w2_17, 4)  STEP4(m2w, w2_18, 8)  STEP4(m2w, w2_19, 12)
        STEP4(m2w, w2_20, 16) STEP4(m2w, w2_21, 20) STEP4(m2w, w2_22, 24) STEP4(m2w, w2_23, 28)
        STEP4(m3, w2_24, 0)  STEP4(m3, w2_25, 4)  STEP4(m3, w2_26, 8)  STEP4(m3, w2_27, 12)
        STEP4(m3, w2_28, 16) STEP4(m3, w2_29, 20) STEP4(m3, w2_30, 24) STEP4(m3, w2_31, 28)
#undef STEP4

        // layer-2 leaky update (numpy op order)
        const float c2 = a + b2c;
        float t2 = 0.9f * m2; t2 = t2 + c2; m2 = t2 - r2;
        r2 = (m2 > 1.0f) ? 1.0f : 0.0f;
        o  = o + r2;
    }

    // (row = r, class = q) -> coalesced store (out + blk*256 + tid)
    out[(size_t)row * NCLS + q] = o;
}

extern "C" void kernel_launch(void* const* d_in, const int* in_sizes, int n_in,
                              void* d_out, int out_size, void* d_ws, size_t ws_size,
                              hipStream_t stream) {
    const float* x  = (const float*)d_in[0];
    const float* W1 = (const float*)d_in[1];
    const float* b1 = (const float*)d_in[2];
    const float* W2 = (const float*)d_in[3];
    const float* b2 = (const float*)d_in[4];
    float* out = (float*)d_out;

    const int batch = in_sizes[0] / IN_DIM;   // 16384
    const int grid  = batch / RPB;            // 512 blocks
    snn_fp32<<<grid, NTHR, 0, stream>>>(x, W1, b1, W2, b2, out);
}